// Round 3
// baseline (86.816 us; speedup 1.0000x reference)
//
#include <hip/hip_runtime.h>

// Problem constants (match reference)
constexpr int B  = 4;
constexpr int C  = 3;
constexpr int F  = 5;
constexpr int HO = 256;
constexpr int WO = 256;
constexpr int HI = HO + F - 1; // 260
constexpr int WI = WO + F - 1; // 260
constexpr int P  = HO * WO;    // 65536 pixels per (b, map)
constexpr int FF = F * F;      // 25

// Each wave of a block handles the SAME 64 pixels but a different chunk of the
// 25 taps (6/6/6/7). Tap indices are compile-time constants via template.
template <int K0, int K1>
__device__ __forceinline__ void compute_taps(
    const float* __restrict__ offXb, const float* __restrict__ offYb,
    const float* __restrict__ maskb,
    const float* __restrict__ vb, const float* __restrict__ hb,
    const float* __restrict__ in0, const float* __restrict__ in1,
    const float* __restrict__ in2,
    int x, int y, float acc[3])
{
    constexpr int NK = K1 - K0;
    float oy[NK], ox[NK], mk[NK];
#pragma unroll
    for (int q = 0; q < NK; ++q) oy[q] = offYb[(K0 + q) * P];
#pragma unroll
    for (int q = 0; q < NK; ++q) ox[q] = offXb[(K0 + q) * P];
#pragma unroll
    for (int q = 0; q < NK; ++q) mk[q] = maskb[(K0 + q) * P];

#pragma unroll
    for (int q = 0; q < NK; ++q) {
        const int k = K0 + q;       // compile-time
        const int i = k / F;        // compile-time
        const int j = k % F;        // compile-time

        // px = clip(offY + x + j - half + 1, 0, WI-1); half = 2
        float px = oy[q] + (float)(x + j - 1);
        px = fminf(fmaxf(px, 0.0f), (float)(WI - 1));
        float py = ox[q] + (float)(y + i - 1);
        py = fminf(fmaxf(py, 0.0f), (float)(HI - 1));

        float lf = floorf(px);
        float tf = floorf(py);
        int l = (int)lf;
        int t = (int)tf;
        int r  = min(l + 1, WI - 1);
        int bt = min(t + 1, HI - 1);
        float wx = 1.0f - (px - lf);
        float wy = 1.0f - (py - tf);

        // vb[i*P], hb[j*P]: repeated same-address loads CSE'd by compiler
        float w = vb[i * P] * hb[j * P] * mk[q];
        float wtl = wx * wy * w;
        float wtr = (1.0f - wx) * wy * w;
        float wbl = wx * (1.0f - wy) * w;
        float wbr = (1.0f - wx) * (1.0f - wy) * w;

        int o_tl = t * WI + l;
        int o_tr = t * WI + r;
        int o_bl = bt * WI + l;
        int o_br = bt * WI + r;

        acc[0] += in0[o_tl] * wtl + in0[o_tr] * wtr + in0[o_bl] * wbl + in0[o_br] * wbr;
        acc[1] += in1[o_tl] * wtl + in1[o_tr] * wtr + in1[o_bl] * wbl + in1[o_br] * wbr;
        acc[2] += in2[o_tl] * wtl + in2[o_tr] * wtr + in2[o_bl] * wbl + in2[o_br] * wbr;
    }
}

__global__ __launch_bounds__(256, 8) void dsepconv_kernel(
    const float* __restrict__ inp,   // (B, C, HI, WI)
    const float* __restrict__ vert,  // (B, F, HO, WO)
    const float* __restrict__ horz,  // (B, F, HO, WO)
    const float* __restrict__ offX,  // (B, F*F, HO, WO)  -> used for py (vertical)
    const float* __restrict__ offY,  // (B, F*F, HO, WO)  -> used for px (horizontal)
    const float* __restrict__ mask,  // (B, F*F, HO, WO)
    float* __restrict__ out)         // (B, C, HO, WO)
{
    const int lane = threadIdx.x & 63;
    const int wave = threadIdx.x >> 6;

    // 64 consecutive global pixels per block (coalesced streaming loads/wave)
    const int idx = blockIdx.x * 64 + lane;   // over B*HO*WO
    const int x = idx & (WO - 1);
    const int y = (idx >> 8) & (HO - 1);
    const int b = idx >> 16;
    const int pix = y * WO + x;

    const float* offXb = offX + (size_t)b * FF * P + pix;
    const float* offYb = offY + (size_t)b * FF * P + pix;
    const float* maskb = mask + (size_t)b * FF * P + pix;
    const float* vb    = vert + (size_t)b * F * P + pix;
    const float* hb    = horz + (size_t)b * F * P + pix;
    const float* in0   = inp  + (size_t)b * C * HI * WI;
    const float* in1   = in0 + HI * WI;
    const float* in2   = in1 + HI * WI;

    float acc[3] = {0.f, 0.f, 0.f};

    switch (wave) {
        case 0: compute_taps<0, 6>(offXb, offYb, maskb, vb, hb, in0, in1, in2, x, y, acc); break;
        case 1: compute_taps<6, 12>(offXb, offYb, maskb, vb, hb, in0, in1, in2, x, y, acc); break;
        case 2: compute_taps<12, 18>(offXb, offYb, maskb, vb, hb, in0, in1, in2, x, y, acc); break;
        default: compute_taps<18, 25>(offXb, offYb, maskb, vb, hb, in0, in1, in2, x, y, acc); break;
    }

    // Reduce 4 wave-partials per pixel via LDS (conflict-free layout)
    __shared__ float lds[4][3][64];
    lds[wave][0][lane] = acc[0];
    lds[wave][1][lane] = acc[1];
    lds[wave][2][lane] = acc[2];
    __syncthreads();

    if (threadIdx.x < 192) {
        const int ch = threadIdx.x >> 6;  // 0..2
        const int ln = threadIdx.x & 63;
        float s = lds[0][ch][ln] + lds[1][ch][ln] + lds[2][ch][ln] + lds[3][ch][ln];
        const int sidx = blockIdx.x * 64 + ln;
        const int sb   = sidx >> 16;
        const int spix = sidx & (P - 1);
        out[(size_t)sb * C * P + (size_t)ch * P + spix] = s;
    }
}

extern "C" void kernel_launch(void* const* d_in, const int* in_sizes, int n_in,
                              void* d_out, int out_size, void* d_ws, size_t ws_size,
                              hipStream_t stream) {
    const float* inp  = (const float*)d_in[0];
    const float* vert = (const float*)d_in[1];
    const float* horz = (const float*)d_in[2];
    const float* offX = (const float*)d_in[3];
    const float* offY = (const float*)d_in[4];
    const float* mask = (const float*)d_in[5];
    float* out = (float*)d_out;

    const int total = B * HO * WO;       // 262144 pixels
    dim3 block(256);
    dim3 grid(total / 64);               // 4096 blocks, 16384 waves
    dsepconv_kernel<<<grid, block, 0, stream>>>(inp, vert, horz, offX, offY, mask, out);
}

// Round 4
// 63.001 us; speedup vs baseline: 1.3780x; 1.3780x over previous
//
#include <hip/hip_runtime.h>

// Problem constants (match reference)
constexpr int B  = 4;
constexpr int C  = 3;
constexpr int F  = 5;
constexpr int HO = 256;
constexpr int WO = 256;
constexpr int HI = HO + F - 1; // 260
constexpr int WI = WO + F - 1; // 260
constexpr int P  = HO * WO;    // 65536 pixels per (b, map)
constexpr int FF = F * F;      // 25

// Tap-split across the 4 waves of a block (6/6/6/7 contiguous taps each);
// 64 consecutive pixels per block. 16384 waves total -> 8 waves/SIMD resident
// (needs <=64 VGPR: NO prefetch arrays, load-and-use per tap, minimal live set).
// Latency hiding via TLP, not per-wave ILP (R3's prefetch arrays spilled).
__global__ __launch_bounds__(256, 8) void dsepconv_kernel(
    const float* __restrict__ inp,   // (B, C, HI, WI)
    const float* __restrict__ vert,  // (B, F, HO, WO)
    const float* __restrict__ horz,  // (B, F, HO, WO)
    const float* __restrict__ offX,  // (B, F*F, HO, WO)  -> used for py (vertical)
    const float* __restrict__ offY,  // (B, F*F, HO, WO)  -> used for px (horizontal)
    const float* __restrict__ mask,  // (B, F*F, HO, WO)
    float* __restrict__ out)         // (B, C, HO, WO)
{
    const int lane = threadIdx.x & 63;
    const int wave = threadIdx.x >> 6;

    const int idx = blockIdx.x * 64 + lane;   // over B*HO*WO
    const int x = idx & (WO - 1);
    const int y = (idx >> 8) & (HO - 1);
    const int b = idx >> 16;
    const int pix = y * WO + x;

    const float* offXb = offX + (size_t)b * FF * P + pix;
    const float* offYb = offY + (size_t)b * FF * P + pix;
    const float* maskb = mask + (size_t)b * FF * P + pix;
    const float* vb    = vert + (size_t)b * F * P + pix;
    const float* hb    = horz + (size_t)b * F * P + pix;
    const float* in0   = inp  + (size_t)b * C * HI * WI;
    const float* in1   = in0 + HI * WI;
    const float* in2   = in1 + HI * WI;

    float acc0 = 0.f, acc1 = 0.f, acc2 = 0.f;

    const int k0 = wave * 6;
    const int k1 = (wave == 3) ? FF : k0 + 6;

    for (int k = k0; k < k1; ++k) {
        const int i = k / F;
        const int j = k - i * F;

        float oy = offYb[k * P];
        float ox = offXb[k * P];
        float m  = maskb[k * P];
        float v  = vb[i * P];
        float h  = hb[j * P];

        // px = clip(offY + x + j - half + 1, 0, WI-1); half = 2
        float px = oy + (float)(x + j - 1);
        px = fminf(fmaxf(px, 0.0f), (float)(WI - 1));
        float py = ox + (float)(y + i - 1);
        py = fminf(fmaxf(py, 0.0f), (float)(HI - 1));

        float lf = floorf(px);
        float tf = floorf(py);
        int l = (int)lf;
        int t = (int)tf;
        int r  = min(l + 1, WI - 1);
        int bt = min(t + 1, HI - 1);
        float wx = 1.0f - (px - lf);
        float wy = 1.0f - (py - tf);

        float w = v * h * m;
        float wtl = wx * wy * w;
        float wtr = (1.0f - wx) * wy * w;
        float wbl = wx * (1.0f - wy) * w;
        float wbr = (1.0f - wx) * (1.0f - wy) * w;

        int o_tl = t * WI + l;
        int o_tr = t * WI + r;
        int o_bl = bt * WI + l;
        int o_br = bt * WI + r;

        acc0 += in0[o_tl] * wtl + in0[o_tr] * wtr + in0[o_bl] * wbl + in0[o_br] * wbr;
        acc1 += in1[o_tl] * wtl + in1[o_tr] * wtr + in1[o_bl] * wbl + in1[o_br] * wbr;
        acc2 += in2[o_tl] * wtl + in2[o_tr] * wtr + in2[o_bl] * wbl + in2[o_br] * wbr;
    }

    // Reduce 4 wave-partials per pixel via LDS (conflict-free layout)
    __shared__ float lds[4][3][64];
    lds[wave][0][lane] = acc0;
    lds[wave][1][lane] = acc1;
    lds[wave][2][lane] = acc2;
    __syncthreads();

    if (threadIdx.x < 192) {
        const int ch = threadIdx.x >> 6;  // 0..2
        const int ln = threadIdx.x & 63;
        float s = lds[0][ch][ln] + lds[1][ch][ln] + lds[2][ch][ln] + lds[3][ch][ln];
        const int sidx = blockIdx.x * 64 + ln;
        const int sb   = sidx >> 16;
        const int spix = sidx & (P - 1);
        out[(size_t)sb * C * P + (size_t)ch * P + spix] = s;
    }
}

extern "C" void kernel_launch(void* const* d_in, const int* in_sizes, int n_in,
                              void* d_out, int out_size, void* d_ws, size_t ws_size,
                              hipStream_t stream) {
    const float* inp  = (const float*)d_in[0];
    const float* vert = (const float*)d_in[1];
    const float* horz = (const float*)d_in[2];
    const float* offX = (const float*)d_in[3];
    const float* offY = (const float*)d_in[4];
    const float* mask = (const float*)d_in[5];
    float* out = (float*)d_out;

    const int total = B * HO * WO;       // 262144 pixels
    dim3 block(256);
    dim3 grid(total / 64);               // 4096 blocks, 16384 waves
    dsepconv_kernel<<<grid, block, 0, stream>>>(inp, vert, horz, offX, offY, mask, out);
}

// Round 5
// 55.626 us; speedup vs baseline: 1.5607x; 1.1326x over previous
//
#include <hip/hip_runtime.h>

// Problem constants (match reference)
constexpr int B  = 4;
constexpr int C  = 3;
constexpr int F  = 5;
constexpr int HO = 256;
constexpr int WO = 256;
constexpr int HI = HO + F - 1; // 260
constexpr int WI = WO + F - 1; // 260
constexpr int P  = HO * WO;    // 65536 pixels per (b, map)
constexpr int FF = F * F;      // 25
constexpr int PI = HI * WI;    // 67600 input pixels per (b, c)

// ---------------- Prolog: NCHW -> NHWC4 (float4, w=0) ----------------
__global__ __launch_bounds__(256) void transpose_kernel(
    const float* __restrict__ inp,  // (B, C, HI, WI)
    float4* __restrict__ nin)       // (B, HI*WI) float4
{
    int idx = blockIdx.x * blockDim.x + threadIdx.x;
    if (idx >= B * PI) return;
    int b = idx / PI;
    int pix = idx - b * PI;
    const float* in0 = inp + (size_t)b * C * PI + pix;
    float4 v;
    v.x = in0[0];
    v.y = in0[PI];
    v.z = in0[2 * PI];
    v.w = 0.0f;
    nin[idx] = v;
}

// ---------------- Main: tap-split across 4 waves, float4 gathers ----------------
template <int K0, int K1>
__device__ __forceinline__ void compute_taps(
    const float* __restrict__ offXb, const float* __restrict__ offYb,
    const float* __restrict__ maskb,
    const float* __restrict__ vb, const float* __restrict__ hb,
    const float4* __restrict__ nin,   // this batch's NHWC4 plane
    int x, int y, float& acc0, float& acc1, float& acc2)
{
#pragma unroll
    for (int k = K0; k < K1; ++k) {
        const int i = k / F;   // compile-time
        const int j = k % F;   // compile-time

        float oy = offYb[k * P];
        float ox = offXb[k * P];
        float m  = maskb[k * P];
        float v  = vb[i * P];
        float h  = hb[j * P];

        // px = clip(offY + x + j - half + 1, 0, WI-1); half = 2
        float px = oy + (float)(x + j - 1);
        px = fminf(fmaxf(px, 0.0f), (float)(WI - 1));
        float py = ox + (float)(y + i - 1);
        py = fminf(fmaxf(py, 0.0f), (float)(HI - 1));

        float lf = floorf(px);
        float tf = floorf(py);
        int l = (int)lf;
        int t = (int)tf;
        int r  = min(l + 1, WI - 1);
        int bt = min(t + 1, HI - 1);
        float wx = 1.0f - (px - lf);
        float wy = 1.0f - (py - tf);

        float w = v * h * m;
        float wtl = wx * wy * w;
        float wtr = (1.0f - wx) * wy * w;
        float wbl = wx * (1.0f - wy) * w;
        float wbr = (1.0f - wx) * (1.0f - wy) * w;

        // 4 float4 gathers (3 channels each) instead of 12 scalar gathers
        float4 g_tl = nin[t * WI + l];
        float4 g_tr = nin[t * WI + r];
        float4 g_bl = nin[bt * WI + l];
        float4 g_br = nin[bt * WI + r];

        acc0 += g_tl.x * wtl + g_tr.x * wtr + g_bl.x * wbl + g_br.x * wbr;
        acc1 += g_tl.y * wtl + g_tr.y * wtr + g_bl.y * wbl + g_br.y * wbr;
        acc2 += g_tl.z * wtl + g_tr.z * wtr + g_bl.z * wbl + g_br.z * wbr;
    }
}

__global__ __launch_bounds__(256, 8) void dsepconv_nhwc_kernel(
    const float4* __restrict__ nin,  // (B, HI*WI) float4 from workspace
    const float* __restrict__ vert,
    const float* __restrict__ horz,
    const float* __restrict__ offX,  // -> py (vertical)
    const float* __restrict__ offY,  // -> px (horizontal)
    const float* __restrict__ mask,
    float* __restrict__ out)
{
    const int lane = threadIdx.x & 63;
    const int wave = threadIdx.x >> 6;

    const int idx = blockIdx.x * 64 + lane;   // over B*HO*WO
    const int x = idx & (WO - 1);
    const int y = (idx >> 8) & (HO - 1);
    const int b = idx >> 16;
    const int pix = y * WO + x;

    const float* offXb = offX + (size_t)b * FF * P + pix;
    const float* offYb = offY + (size_t)b * FF * P + pix;
    const float* maskb = mask + (size_t)b * FF * P + pix;
    const float* vb    = vert + (size_t)b * F * P + pix;
    const float* hb    = horz + (size_t)b * F * P + pix;
    const float4* ninb = nin + (size_t)b * PI;

    float acc0 = 0.f, acc1 = 0.f, acc2 = 0.f;

    switch (wave) {
        case 0: compute_taps<0, 6>(offXb, offYb, maskb, vb, hb, ninb, x, y, acc0, acc1, acc2); break;
        case 1: compute_taps<6, 12>(offXb, offYb, maskb, vb, hb, ninb, x, y, acc0, acc1, acc2); break;
        case 2: compute_taps<12, 18>(offXb, offYb, maskb, vb, hb, ninb, x, y, acc0, acc1, acc2); break;
        default: compute_taps<18, 25>(offXb, offYb, maskb, vb, hb, ninb, x, y, acc0, acc1, acc2); break;
    }

    // Reduce 4 wave-partials per pixel via LDS (2-way = free)
    __shared__ float lds[4][3][64];
    lds[wave][0][lane] = acc0;
    lds[wave][1][lane] = acc1;
    lds[wave][2][lane] = acc2;
    __syncthreads();

    if (threadIdx.x < 192) {
        const int ch = threadIdx.x >> 6;  // 0..2
        const int ln = threadIdx.x & 63;
        float s = lds[0][ch][ln] + lds[1][ch][ln] + lds[2][ch][ln] + lds[3][ch][ln];
        const int sidx = blockIdx.x * 64 + ln;
        const int sb   = sidx >> 16;
        const int spix = sidx & (P - 1);
        out[(size_t)sb * C * P + (size_t)ch * P + spix] = s;
    }
}

// ---------------- Fallback (R4): NCHW scalar gathers, no workspace ----------------
__global__ __launch_bounds__(256, 8) void dsepconv_nchw_kernel(
    const float* __restrict__ inp,
    const float* __restrict__ vert,
    const float* __restrict__ horz,
    const float* __restrict__ offX,
    const float* __restrict__ offY,
    const float* __restrict__ mask,
    float* __restrict__ out)
{
    const int lane = threadIdx.x & 63;
    const int wave = threadIdx.x >> 6;
    const int idx = blockIdx.x * 64 + lane;
    const int x = idx & (WO - 1);
    const int y = (idx >> 8) & (HO - 1);
    const int b = idx >> 16;
    const int pix = y * WO + x;

    const float* offXb = offX + (size_t)b * FF * P + pix;
    const float* offYb = offY + (size_t)b * FF * P + pix;
    const float* maskb = mask + (size_t)b * FF * P + pix;
    const float* vb    = vert + (size_t)b * F * P + pix;
    const float* hb    = horz + (size_t)b * F * P + pix;
    const float* in0   = inp  + (size_t)b * C * PI;
    const float* in1   = in0 + PI;
    const float* in2   = in1 + PI;

    float acc0 = 0.f, acc1 = 0.f, acc2 = 0.f;
    const int k0 = wave * 6;
    const int k1 = (wave == 3) ? FF : k0 + 6;

    for (int k = k0; k < k1; ++k) {
        const int i = k / F;
        const int j = k - i * F;
        float oy = offYb[k * P];
        float ox = offXb[k * P];
        float m  = maskb[k * P];
        float v  = vb[i * P];
        float h  = hb[j * P];
        float px = oy + (float)(x + j - 1);
        px = fminf(fmaxf(px, 0.0f), (float)(WI - 1));
        float py = ox + (float)(y + i - 1);
        py = fminf(fmaxf(py, 0.0f), (float)(HI - 1));
        float lf = floorf(px);
        float tf = floorf(py);
        int l = (int)lf;
        int t = (int)tf;
        int r  = min(l + 1, WI - 1);
        int bt = min(t + 1, HI - 1);
        float wx = 1.0f - (px - lf);
        float wy = 1.0f - (py - tf);
        float w = v * h * m;
        float wtl = wx * wy * w;
        float wtr = (1.0f - wx) * wy * w;
        float wbl = wx * (1.0f - wy) * w;
        float wbr = (1.0f - wx) * (1.0f - wy) * w;
        int o_tl = t * WI + l;
        int o_tr = t * WI + r;
        int o_bl = bt * WI + l;
        int o_br = bt * WI + r;
        acc0 += in0[o_tl] * wtl + in0[o_tr] * wtr + in0[o_bl] * wbl + in0[o_br] * wbr;
        acc1 += in1[o_tl] * wtl + in1[o_tr] * wtr + in1[o_bl] * wbl + in1[o_br] * wbr;
        acc2 += in2[o_tl] * wtl + in2[o_tr] * wtr + in2[o_bl] * wbl + in2[o_br] * wbr;
    }

    __shared__ float lds[4][3][64];
    lds[wave][0][lane] = acc0;
    lds[wave][1][lane] = acc1;
    lds[wave][2][lane] = acc2;
    __syncthreads();

    if (threadIdx.x < 192) {
        const int ch = threadIdx.x >> 6;
        const int ln = threadIdx.x & 63;
        float s = lds[0][ch][ln] + lds[1][ch][ln] + lds[2][ch][ln] + lds[3][ch][ln];
        const int sidx = blockIdx.x * 64 + ln;
        const int sb   = sidx >> 16;
        const int spix = sidx & (P - 1);
        out[(size_t)sb * C * P + (size_t)ch * P + spix] = s;
    }
}

extern "C" void kernel_launch(void* const* d_in, const int* in_sizes, int n_in,
                              void* d_out, int out_size, void* d_ws, size_t ws_size,
                              hipStream_t stream) {
    const float* inp  = (const float*)d_in[0];
    const float* vert = (const float*)d_in[1];
    const float* horz = (const float*)d_in[2];
    const float* offX = (const float*)d_in[3];
    const float* offY = (const float*)d_in[4];
    const float* mask = (const float*)d_in[5];
    float* out = (float*)d_out;

    const int total = B * HO * WO;           // 262144 pixels
    const size_t need = (size_t)B * PI * sizeof(float4); // 4.33 MB

    if (ws_size >= need) {
        float4* nin = (float4*)d_ws;
        int tthreads = B * PI;               // 1,081,600
        transpose_kernel<<<(tthreads + 255) / 256, 256, 0, stream>>>(inp, nin);
        dsepconv_nhwc_kernel<<<total / 64, 256, 0, stream>>>(nin, vert, horz, offX, offY, mask, out);
    } else {
        dsepconv_nchw_kernel<<<total / 64, 256, 0, stream>>>(inp, vert, horz, offX, offY, mask, out);
    }
}

// Round 6
// 41.015 us; speedup vs baseline: 2.1167x; 1.3562x over previous
//
#include <hip/hip_runtime.h>

// Problem constants (match reference)
constexpr int B  = 4;
constexpr int C  = 3;
constexpr int F  = 5;
constexpr int HO = 256;
constexpr int WO = 256;
constexpr int HI = HO + F - 1; // 260
constexpr int WI = WO + F - 1; // 260
constexpr int P  = HO * WO;    // 65536 pixels per (b, map)
constexpr int FF = F * F;      // 25
constexpr int PI = HI * WI;    // 67600 input pixels per (b, c)

// ---------------- Prolog: NCHW -> NHWC4 (float4, w=0) ----------------
__global__ __launch_bounds__(256) void transpose_kernel(
    const float* __restrict__ inp,  // (B, C, HI, WI)
    float4* __restrict__ nin)       // (B, HI*WI) float4
{
    int idx = blockIdx.x * blockDim.x + threadIdx.x;
    if (idx >= B * PI) return;
    int b = idx / PI;
    int pix = idx - b * PI;
    const float* in0 = inp + (size_t)b * C * PI + pix;
    float4 v;
    v.x = in0[0];
    v.y = in0[PI];
    v.z = in0[2 * PI];
    v.w = 0.0f;
    nin[idx] = v;
}

// ---------------- Main: 5 waves/block, one filter ROW per wave ----------------
// Block = 320 threads = 5 waves; wave w handles filter row i=w (5 taps).
// 64 consecutive pixels per block. Runtime j-loop, load-and-use (NO unroll:
// R3/R5 showed hipcc hoist-spills unrolled tap batches). Latency hidden by
// TLP: 6 blocks/CU = 30 waves/CU.
__global__ __launch_bounds__(320, 8) void dsepconv_nhwc_kernel(
    const float4* __restrict__ nin,  // (B, HI*WI) float4 from workspace
    const float* __restrict__ vert,
    const float* __restrict__ horz,
    const float* __restrict__ offX,  // -> py (vertical)
    const float* __restrict__ offY,  // -> px (horizontal)
    const float* __restrict__ mask,
    float* __restrict__ out)
{
    const int lane = threadIdx.x & 63;
    const int wave = threadIdx.x >> 6;        // 0..4 == filter row i

    const int idx = blockIdx.x * 64 + lane;   // over B*HO*WO
    const int x = idx & (WO - 1);
    const int y = (idx >> 8) & (HO - 1);
    const int b = idx >> 16;
    const int pix = y * WO + x;

    const float* offXb = offX + (size_t)b * FF * P + pix;
    const float* offYb = offY + (size_t)b * FF * P + pix;
    const float* maskb = mask + (size_t)b * FF * P + pix;
    const float* vb    = vert + (size_t)b * F * P + pix;
    const float* hb    = horz + (size_t)b * F * P + pix;
    const float4* ninb = nin + (size_t)b * PI;

    const int i = wave;
    const float v = vb[i * P];                        // vertical: once per wave
    const float py_base = (float)(y + i - 1);

    float acc0 = 0.f, acc1 = 0.f, acc2 = 0.f;

#pragma unroll 1
    for (int j = 0; j < F; ++j) {
        const int k = i * F + j;

        float oy = offYb[k * P];
        float ox = offXb[k * P];
        float m  = maskb[k * P];
        float h  = hb[j * P];

        // px = clip(offY + x + j - half + 1, 0, WI-1); half = 2
        float px = oy + (float)(x + j - 1);
        px = fminf(fmaxf(px, 0.0f), (float)(WI - 1));
        float py = ox + py_base;
        py = fminf(fmaxf(py, 0.0f), (float)(HI - 1));

        float lf = floorf(px);
        float tf = floorf(py);
        int l = (int)lf;
        int t = (int)tf;
        int r  = min(l + 1, WI - 1);
        int bt = min(t + 1, HI - 1);
        float wx = 1.0f - (px - lf);
        float wy = 1.0f - (py - tf);

        float w = v * h * m;
        float wtl = wx * wy * w;
        float wtr = (1.0f - wx) * wy * w;
        float wbl = wx * (1.0f - wy) * w;
        float wbr = (1.0f - wx) * (1.0f - wy) * w;

        // 4 float4 gathers (3 channels each), independent -> issue together
        float4 g_tl = ninb[t * WI + l];
        float4 g_tr = ninb[t * WI + r];
        float4 g_bl = ninb[bt * WI + l];
        float4 g_br = ninb[bt * WI + r];

        acc0 += g_tl.x * wtl + g_tr.x * wtr + g_bl.x * wbl + g_br.x * wbr;
        acc1 += g_tl.y * wtl + g_tr.y * wtr + g_bl.y * wbl + g_br.y * wbr;
        acc2 += g_tl.z * wtl + g_tr.z * wtr + g_bl.z * wbl + g_br.z * wbr;
    }

    // Reduce 5 wave-partials per pixel via LDS
    __shared__ float lds[5][3][64];
    lds[wave][0][lane] = acc0;
    lds[wave][1][lane] = acc1;
    lds[wave][2][lane] = acc2;
    __syncthreads();

    if (threadIdx.x < 192) {
        const int ch = threadIdx.x >> 6;  // 0..2
        const int ln = threadIdx.x & 63;
        float s = lds[0][ch][ln] + lds[1][ch][ln] + lds[2][ch][ln]
                + lds[3][ch][ln] + lds[4][ch][ln];
        const int sidx = blockIdx.x * 64 + ln;
        const int sb   = sidx >> 16;
        const int spix = sidx & (P - 1);
        out[(size_t)sb * C * P + (size_t)ch * P + spix] = s;
    }
}

// ---------------- Fallback: NCHW scalar gathers (no workspace) ----------------
__global__ __launch_bounds__(320, 8) void dsepconv_nchw_kernel(
    const float* __restrict__ inp,
    const float* __restrict__ vert,
    const float* __restrict__ horz,
    const float* __restrict__ offX,
    const float* __restrict__ offY,
    const float* __restrict__ mask,
    float* __restrict__ out)
{
    const int lane = threadIdx.x & 63;
    const int wave = threadIdx.x >> 6;
    const int idx = blockIdx.x * 64 + lane;
    const int x = idx & (WO - 1);
    const int y = (idx >> 8) & (HO - 1);
    const int b = idx >> 16;
    const int pix = y * WO + x;

    const float* offXb = offX + (size_t)b * FF * P + pix;
    const float* offYb = offY + (size_t)b * FF * P + pix;
    const float* maskb = mask + (size_t)b * FF * P + pix;
    const float* vb    = vert + (size_t)b * F * P + pix;
    const float* hb    = horz + (size_t)b * F * P + pix;
    const float* in0   = inp  + (size_t)b * C * PI;
    const float* in1   = in0 + PI;
    const float* in2   = in1 + PI;

    const int i = wave;
    const float v = vb[i * P];
    const float py_base = (float)(y + i - 1);

    float acc0 = 0.f, acc1 = 0.f, acc2 = 0.f;

#pragma unroll 1
    for (int j = 0; j < F; ++j) {
        const int k = i * F + j;
        float oy = offYb[k * P];
        float ox = offXb[k * P];
        float m  = maskb[k * P];
        float h  = hb[j * P];
        float px = oy + (float)(x + j - 1);
        px = fminf(fmaxf(px, 0.0f), (float)(WI - 1));
        float py = ox + py_base;
        py = fminf(fmaxf(py, 0.0f), (float)(HI - 1));
        float lf = floorf(px);
        float tf = floorf(py);
        int l = (int)lf;
        int t = (int)tf;
        int r  = min(l + 1, WI - 1);
        int bt = min(t + 1, HI - 1);
        float wx = 1.0f - (px - lf);
        float wy = 1.0f - (py - tf);
        float w = v * h * m;
        float wtl = wx * wy * w;
        float wtr = (1.0f - wx) * wy * w;
        float wbl = wx * (1.0f - wy) * w;
        float wbr = (1.0f - wx) * (1.0f - wy) * w;
        int o_tl = t * WI + l;
        int o_tr = t * WI + r;
        int o_bl = bt * WI + l;
        int o_br = bt * WI + r;
        acc0 += in0[o_tl] * wtl + in0[o_tr] * wtr + in0[o_bl] * wbl + in0[o_br] * wbr;
        acc1 += in1[o_tl] * wtl + in1[o_tr] * wtr + in1[o_bl] * wbl + in1[o_br] * wbr;
        acc2 += in2[o_tl] * wtl + in2[o_tr] * wtr + in2[o_bl] * wbl + in2[o_br] * wbr;
    }

    __shared__ float lds[5][3][64];
    lds[wave][0][lane] = acc0;
    lds[wave][1][lane] = acc1;
    lds[wave][2][lane] = acc2;
    __syncthreads();

    if (threadIdx.x < 192) {
        const int ch = threadIdx.x >> 6;
        const int ln = threadIdx.x & 63;
        float s = lds[0][ch][ln] + lds[1][ch][ln] + lds[2][ch][ln]
                + lds[3][ch][ln] + lds[4][ch][ln];
        const int sidx = blockIdx.x * 64 + ln;
        const int sb   = sidx >> 16;
        const int spix = sidx & (P - 1);
        out[(size_t)sb * C * P + (size_t)ch * P + spix] = s;
    }
}

extern "C" void kernel_launch(void* const* d_in, const int* in_sizes, int n_in,
                              void* d_out, int out_size, void* d_ws, size_t ws_size,
                              hipStream_t stream) {
    const float* inp  = (const float*)d_in[0];
    const float* vert = (const float*)d_in[1];
    const float* horz = (const float*)d_in[2];
    const float* offX = (const float*)d_in[3];
    const float* offY = (const float*)d_in[4];
    const float* mask = (const float*)d_in[5];
    float* out = (float*)d_out;

    const int total = B * HO * WO;                        // 262144 pixels
    const size_t need = (size_t)B * PI * sizeof(float4);  // 4.33 MB

    if (ws_size >= need) {
        float4* nin = (float4*)d_ws;
        int tthreads = B * PI;                            // 270,400
        transpose_kernel<<<(tthreads + 255) / 256, 256, 0, stream>>>(inp, nin);
        dsepconv_nhwc_kernel<<<total / 64, 320, 0, stream>>>(nin, vert, horz, offX, offY, mask, out);
    } else {
        dsepconv_nchw_kernel<<<total / 64, 320, 0, stream>>>(inp, vert, horz, offX, offY, mask, out);
    }
}

// Round 7
// 29.919 us; speedup vs baseline: 2.9017x; 1.3709x over previous
//
#include <hip/hip_runtime.h>

// Problem constants (match reference)
constexpr int B  = 4;
constexpr int C  = 3;
constexpr int F  = 5;
constexpr int HO = 256;
constexpr int WO = 256;
constexpr int HI = HO + F - 1; // 260
constexpr int WI = WO + F - 1; // 260
constexpr int P  = HO * WO;    // 65536 pixels per (b, map)
constexpr int FF = F * F;      // 25
constexpr int PI = HI * WI;    // 67600 input pixels per (b, c)

// LDS tile geometry: block covers 64 consecutive x at one y.
// Samples: py in [y-1+N, y+3+N], px in [x-1+N, x+3+N], N ~ N(0,1).
// Tile rows [y-7, y+10] (18), cols [x0-7, x0+72] (80) covers |N| <= ~6
// (P(|N|>6) ~ 1e-9); out-of-tile lanes take a rare global-load fallback,
// so correctness never depends on the bound.
constexpr int TROWS = 18;
constexpr int TCOLS = 80;
constexpr int TSTRIDE = 81;   // +1 pad: adjacent rows shift banks by 4
constexpr int TN = TROWS * TCOLS; // 1440 entries to stage

// 5 waves/block, wave w = filter row i. All waves gather from the shared tile.
// Runtime j-loop, load-and-use (unrolled tap batches hoist-spill: R3/R5).
__global__ __launch_bounds__(320, 8) void dsepconv_kernel(
    const float* __restrict__ inp,   // (B, C, HI, WI)
    const float* __restrict__ vert,  // (B, F, HO, WO)
    const float* __restrict__ horz,  // (B, F, HO, WO)
    const float* __restrict__ offX,  // -> py (vertical), per reference
    const float* __restrict__ offY,  // -> px (horizontal), per reference
    const float* __restrict__ mask,  // (B, F*F, HO, WO)
    float* __restrict__ out)         // (B, C, HO, WO)
{
    __shared__ float4 tile[TROWS * TSTRIDE]; // 23,328 B; reduce buffer reuses it

    const int tid  = threadIdx.x;
    const int lane = tid & 63;
    const int wave = tid >> 6;                // 0..4 == filter row i

    const int idx0 = blockIdx.x * 64;         // first pixel of this block
    const int idx  = idx0 + lane;
    const int x    = idx & (WO - 1);
    const int y    = (idx >> 8) & (HO - 1);
    const int b    = idx >> 16;
    const int x0   = idx0 & (WO - 1);
    const int pix  = y * WO + x;

    const float* in0 = inp + (size_t)b * C * PI;
    const float* in1 = in0 + PI;
    const float* in2 = in1 + PI;

    // ---- Stage tile: rows [y-7, y+10], cols [x0-7, x0+72], NCHW -> float4 ----
    const int ry0 = y - 7;
    const int cx0 = x0 - 7;
#pragma unroll 1
    for (int e = tid; e < TN; e += 320) {
        int trow = e / TCOLS;
        int tcol = e - trow * TCOLS;
        int gy = min(max(ry0 + trow, 0), HI - 1);
        int gx = min(max(cx0 + tcol, 0), WI - 1);
        int g = gy * WI + gx;
        tile[trow * TSTRIDE + tcol] = make_float4(in0[g], in1[g], in2[g], 0.0f);
    }
    __syncthreads();

    const float* offXb = offX + (size_t)b * FF * P + pix;
    const float* offYb = offY + (size_t)b * FF * P + pix;
    const float* maskb = mask + (size_t)b * FF * P + pix;
    const float* vb    = vert + (size_t)b * F * P + pix;
    const float* hb    = horz + (size_t)b * F * P + pix;

    const int i = wave;
    const float v = vb[i * P];
    const float py_base = (float)(y + i - 1);

    float acc0 = 0.f, acc1 = 0.f, acc2 = 0.f;

#pragma unroll 1
    for (int j = 0; j < F; ++j) {
        const int k = i * F + j;

        float oy = offYb[k * P];
        float ox = offXb[k * P];
        float m  = maskb[k * P];
        float h  = hb[j * P];

        // px = clip(offY + x + j - half + 1, 0, WI-1); half = 2
        float px = fminf(fmaxf(oy + (float)(x + j - 1), 0.0f), (float)(WI - 1));
        float py = fminf(fmaxf(ox + py_base, 0.0f), (float)(HI - 1));

        float lf = floorf(px);
        float tf = floorf(py);
        int l = (int)lf;
        int t = (int)tf;
        int r  = min(l + 1, WI - 1);
        int bt = min(t + 1, HI - 1);
        float wx = 1.0f - (px - lf);
        float wy = 1.0f - (py - tf);

        float w = v * h * m;
        float wtl = wx * wy * w;
        float wtr = (1.0f - wx) * wy * w;
        float wbl = wx * (1.0f - wy) * w;
        float wbr = (1.0f - wx) * (1.0f - wy) * w;

        // local tile coords
        int lt = t - ry0, lb = bt - ry0, ll = l - cx0, lr = r - cx0;
        bool ok = (lt >= 0) & (lb <= TROWS - 1) & (ll >= 0) & (lr <= TCOLS - 1);

        // clamped LDS gather (safe addresses even for !ok lanes)
        int clt = min(max(lt, 0), TROWS - 1);
        int clb = min(max(lb, 0), TROWS - 1);
        int cll = min(max(ll, 0), TCOLS - 1);
        int clr = min(max(lr, 0), TCOLS - 1);

        float4 g_tl = tile[clt * TSTRIDE + cll];
        float4 g_tr = tile[clt * TSTRIDE + clr];
        float4 g_bl = tile[clb * TSTRIDE + cll];
        float4 g_br = tile[clb * TSTRIDE + clr];

        // rare fallback: offset beyond tile margin (~never; keeps correctness)
        if (__any(!ok)) {
            if (!ok) {
                int o_tl = t * WI + l,  o_tr = t * WI + r;
                int o_bl = bt * WI + l, o_br = bt * WI + r;
                g_tl = make_float4(in0[o_tl], in1[o_tl], in2[o_tl], 0.f);
                g_tr = make_float4(in0[o_tr], in1[o_tr], in2[o_tr], 0.f);
                g_bl = make_float4(in0[o_bl], in1[o_bl], in2[o_bl], 0.f);
                g_br = make_float4(in0[o_br], in1[o_br], in2[o_br], 0.f);
            }
        }

        acc0 += g_tl.x * wtl + g_tr.x * wtr + g_bl.x * wbl + g_br.x * wbr;
        acc1 += g_tl.y * wtl + g_tr.y * wtr + g_bl.y * wbl + g_br.y * wbr;
        acc2 += g_tl.z * wtl + g_tr.z * wtr + g_bl.z * wbl + g_br.z * wbr;
    }

    // ---- Reduce 5 wave-partials per pixel; reuse dead tile LDS ----
    __syncthreads();                     // all gathers done before overwrite
    float* red = (float*)tile;           // [5][3][64] floats = 3840 B
    red[(wave * 3 + 0) * 64 + lane] = acc0;
    red[(wave * 3 + 1) * 64 + lane] = acc1;
    red[(wave * 3 + 2) * 64 + lane] = acc2;
    __syncthreads();

    if (tid < 192) {
        const int ch = tid >> 6;  // 0..2
        const int ln = tid & 63;
        float s = red[(0 * 3 + ch) * 64 + ln]
                + red[(1 * 3 + ch) * 64 + ln]
                + red[(2 * 3 + ch) * 64 + ln]
                + red[(3 * 3 + ch) * 64 + ln]
                + red[(4 * 3 + ch) * 64 + ln];
        const int sidx = idx0 + ln;
        const int sb   = sidx >> 16;
        const int spix = sidx & (P - 1);
        out[(size_t)sb * C * P + (size_t)ch * P + spix] = s;
    }
}

extern "C" void kernel_launch(void* const* d_in, const int* in_sizes, int n_in,
                              void* d_out, int out_size, void* d_ws, size_t ws_size,
                              hipStream_t stream) {
    const float* inp  = (const float*)d_in[0];
    const float* vert = (const float*)d_in[1];
    const float* horz = (const float*)d_in[2];
    const float* offX = (const float*)d_in[3];
    const float* offY = (const float*)d_in[4];
    const float* mask = (const float*)d_in[5];
    float* out = (float*)d_out;

    const int total = B * HO * WO;       // 262144 pixels
    dim3 block(320);
    dim3 grid(total / 64);               // 4096 blocks
    dsepconv_kernel<<<grid, block, 0, stream>>>(inp, vert, horz, offX, offY, mask, out);
}

// Round 8
// 27.027 us; speedup vs baseline: 3.2122x; 1.1070x over previous
//
#include <hip/hip_runtime.h>
#include <hip/hip_fp16.h>

// Problem constants (match reference)
constexpr int B  = 4;
constexpr int C  = 3;
constexpr int F  = 5;
constexpr int HO = 256;
constexpr int WO = 256;
constexpr int HI = HO + F - 1; // 260
constexpr int WI = WO + F - 1; // 260
constexpr int P  = HO * WO;    // 65536 pixels per (b, map)
constexpr int FF = F * F;      // 25
constexpr int PI = HI * WI;    // 67600 input pixels per (b, c)

// LDS tile: rows [y-7, y+10] (18), cols [x0-7, x0+72] (80); fp16-packed
// 3 channels per pixel in 8 B (uint2). Out-of-tile offsets (P ~ 1e-9 per
// sample) take a rare global fallback — correctness never depends on margin.
constexpr int TROWS = 18;
constexpr int TCOLS = 80;
constexpr int TSTRIDE = 81;            // 8B units; rows shift bank-groups by 1
constexpr int TN = TROWS * TCOLS;      // 1440 entries
// max clamped base index so that +1, +TSTRIDE, +TSTRIDE+1 stay in-array
constexpr int AMAX = (TROWS - 2) * TSTRIDE + (TCOLS - 2);

__device__ __forceinline__ uint2 pack3(float a, float b, float c) {
    __half2 ab = __floats2half2_rn(a, b);
    __half2 cz = __floats2half2_rn(c, 0.0f);
    uint2 r;
    r.x = *reinterpret_cast<const unsigned int*>(&ab);
    r.y = *reinterpret_cast<const unsigned int*>(&cz);
    return r;
}

__device__ __forceinline__ void fmacc(uint2 v, float w,
                                      float& a0, float& a1, float& a2) {
    __half2 ab = *reinterpret_cast<const __half2*>(&v.x);
    __half2 cz = *reinterpret_cast<const __half2*>(&v.y);
    // (float)half * f32 + f32 acc -> v_fma_mix_f32
    a0 += __half2float(__low2half(ab))  * w;
    a1 += __half2float(__high2half(ab)) * w;
    a2 += __half2float(__low2half(cz))  * w;
}

// 5 waves/block, wave = filter row i; 64 consecutive pixels per block.
// Runtime j-loop, load-and-use (unrolled tap batches hoist-spill: R3/R5).
__global__ __launch_bounds__(320, 8) void dsepconv_kernel(
    const float* __restrict__ inp,   // (B, C, HI, WI)
    const float* __restrict__ vert,  // (B, F, HO, WO)
    const float* __restrict__ horz,  // (B, F, HO, WO)
    const float* __restrict__ offX,  // -> py (vertical), per reference
    const float* __restrict__ offY,  // -> px (horizontal), per reference
    const float* __restrict__ mask,  // (B, F*F, HO, WO)
    float* __restrict__ out)         // (B, C, HO, WO)
{
    __shared__ uint2 tileq[TROWS * TSTRIDE];  // 11,664 B; reduce buf reuses it

    const int tid  = threadIdx.x;
    const int lane = tid & 63;
    const int wave = tid >> 6;                 // 0..4 == filter row i

    const int idx0 = blockIdx.x * 64;          // first pixel of this block
    const int idx  = idx0 + lane;
    const int x    = idx & (WO - 1);
    const int y    = (idx >> 8) & (HO - 1);
    const int b    = idx >> 16;
    const int x0   = idx0 & (WO - 1);
    const int pix  = y * WO + x;

    const float* in0 = inp + (size_t)b * C * PI;
    const float* in1 = in0 + PI;
    const float* in2 = in1 + PI;

    // ---- Stage tile (fp16 pack): rows [y-7, y+10], cols [x0-7, x0+72] ----
    const int ry0 = y - 7;
    const int cx0 = x0 - 7;
#pragma unroll 1
    for (int e = tid; e < TN; e += 320) {
        int trow = e / TCOLS;
        int tcol = e - trow * TCOLS;
        int gy = min(max(ry0 + trow, 0), HI - 1);
        int gx = min(max(cx0 + tcol, 0), WI - 1);
        int g = gy * WI + gx;
        tileq[trow * TSTRIDE + tcol] = pack3(in0[g], in1[g], in2[g]);
    }
    __syncthreads();

    const float* offXb = offX + (size_t)b * FF * P + pix;
    const float* offYb = offY + (size_t)b * FF * P + pix;
    const float* maskb = mask + (size_t)b * FF * P + pix;
    const float* vb    = vert + (size_t)b * F * P + pix;
    const float* hb    = horz + (size_t)b * F * P + pix;

    const int i = wave;
    const float v = vb[i * P];
    const float py_base = (float)(y + i - 1);

    float acc0 = 0.f, acc1 = 0.f, acc2 = 0.f;

#pragma unroll 1
    for (int j = 0; j < F; ++j) {
        const int k = i * F + j;

        float oy = offYb[k * P];
        float ox = offXb[k * P];
        float m  = maskb[k * P];
        float h  = hb[j * P];

        // px = clip(offY + x + j - half + 1, 0, WI-1); half = 2
        float px = fminf(fmaxf(oy + (float)(x + j - 1), 0.0f), (float)(WI - 1));
        float py = fminf(fmaxf(ox + py_base, 0.0f), (float)(HI - 1));

        float lf = floorf(px);
        float tf = floorf(py);
        int l = (int)lf;
        int t = (int)tf;
        float wx = 1.0f - (px - lf);
        float wy = 1.0f - (py - tf);

        // Bilinear identity: when px==WI-1, wx==1 so the (l+1) column has
        // weight exactly 0 (same for py bottom row) -> always read l+1/t+1.
        float w   = v * h * m;
        float wyw = wy * w;
        float wbw = w - wyw;
        float wtl = wx * wyw;
        float wtr = wyw - wtl;
        float wbl = wx * wbw;
        float wbr = wbw - wbl;

        int lt = t - ry0;
        int ll = l - cx0;
        bool ok = ((unsigned)lt <= TROWS - 2) & ((unsigned)ll <= TCOLS - 2);

        int a = min(max(lt * TSTRIDE + ll, 0), AMAX); // safe for !ok lanes

        uint2 g_tl = tileq[a];
        uint2 g_tr = tileq[a + 1];
        uint2 g_bl = tileq[a + TSTRIDE];
        uint2 g_br = tileq[a + TSTRIDE + 1];

        // rare fallback: offset beyond tile margin (~1e-9/sample)
        if (__any(!ok)) {
            if (!ok) {
                int r  = min(l + 1, WI - 1);
                int bt = min(t + 1, HI - 1);
                int o_tl = t * WI + l,  o_tr = t * WI + r;
                int o_bl = bt * WI + l, o_br = bt * WI + r;
                g_tl = pack3(in0[o_tl], in1[o_tl], in2[o_tl]);
                g_tr = pack3(in0[o_tr], in1[o_tr], in2[o_tr]);
                g_bl = pack3(in0[o_bl], in1[o_bl], in2[o_bl]);
                g_br = pack3(in0[o_br], in1[o_br], in2[o_br]);
            }
        }

        fmacc(g_tl, wtl, acc0, acc1, acc2);
        fmacc(g_tr, wtr, acc0, acc1, acc2);
        fmacc(g_bl, wbl, acc0, acc1, acc2);
        fmacc(g_br, wbr, acc0, acc1, acc2);
    }

    // ---- Reduce 5 wave-partials per pixel; reuse dead tile LDS ----
    __syncthreads();                      // all gathers done before overwrite
    float* red = (float*)tileq;           // [5][3][64] floats = 3840 B
    red[(wave * 3 + 0) * 64 + lane] = acc0;
    red[(wave * 3 + 1) * 64 + lane] = acc1;
    red[(wave * 3 + 2) * 64 + lane] = acc2;
    __syncthreads();

    if (tid < 192) {
        const int ch = tid >> 6;  // 0..2
        const int ln = tid & 63;
        float s = red[(0 * 3 + ch) * 64 + ln]
                + red[(1 * 3 + ch) * 64 + ln]
                + red[(2 * 3 + ch) * 64 + ln]
                + red[(3 * 3 + ch) * 64 + ln]
                + red[(4 * 3 + ch) * 64 + ln];
        const int sidx = idx0 + ln;
        const int sb   = sidx >> 16;
        const int spix = sidx & (P - 1);
        out[(size_t)sb * C * P + (size_t)ch * P + spix] = s;
    }
}

extern "C" void kernel_launch(void* const* d_in, const int* in_sizes, int n_in,
                              void* d_out, int out_size, void* d_ws, size_t ws_size,
                              hipStream_t stream) {
    const float* inp  = (const float*)d_in[0];
    const float* vert = (const float*)d_in[1];
    const float* horz = (const float*)d_in[2];
    const float* offX = (const float*)d_in[3];
    const float* offY = (const float*)d_in[4];
    const float* mask = (const float*)d_in[5];
    float* out = (float*)d_out;

    const int total = B * HO * WO;       // 262144 pixels
    dim3 block(320);
    dim3 grid(total / 64);               // 4096 blocks
    dsepconv_kernel<<<grid, block, 0, stream>>>(inp, vert, horz, offX, offY, mask, out);
}